// Round 4
// baseline (45.112 us; speedup 1.0000x reference)
//
#include <hip/hip_runtime.h>

// RandomShift: out[b,t] = in[b, t - s_b] if 0 <= t - s_b < T else 0.
// B=2048, T=16000, fp32. Memory-bound: ~262 MB total traffic.
//
// R1: uniform-tile fast path (shift is block-uniform) -> one unaligned
//     dwordx4 load per thread, no per-element checks. 43.7 us, ~6.0 TB/s.
// R2/R3: nontemporal load/store hints — both streams are touch-once and
//     jointly exceed the 256 MB L3, so cache retention is pure thrash.
//     (R3 fixes R2's compile error: builtin needs clang ext_vector types,
//     not HIP_vector_type float4.)

constexpr int BATCH = 2048;
constexpr int TIME = 16000;
constexpr int EPT = 4;            // elements per thread
constexpr int BLOCK = 256;
constexpr int TILE = BLOCK * EPT; // 1024

// Clang ext-vector float4 with only 4-byte alignment (misaligned wide load).
typedef float f4u __attribute__((ext_vector_type(4), aligned(4)));
// Clang ext-vector float4, naturally 16B-aligned (for the store).
typedef float f4a __attribute__((ext_vector_type(4)));

__global__ __launch_bounds__(BLOCK) void random_shift_kernel(
    const float* __restrict__ in,
    const int* __restrict__ shifts,
    float* __restrict__ out) {
    const int b = blockIdx.y;
    const int s = shifts[b];  // uniform per block -> scalar
    const int tile0 = blockIdx.x * TILE;
    const int t0 = tile0 + threadIdx.x * EPT;
    if (t0 >= TIME) return;

    const float* __restrict__ row_in = in + (size_t)b * TIME;
    const int tile_end = (tile0 + TILE < TIME) ? (tile0 + TILE) : TIME;

    f4a v;
    if (tile0 - s >= 0 && tile_end - s <= TIME) {
        // Whole tile maps to valid sources: single wide load, no checks.
        f4u lv = __builtin_nontemporal_load(
            reinterpret_cast<const f4u*>(row_in + (t0 - s)));
        v.x = lv.x; v.y = lv.y; v.z = lv.z; v.w = lv.w;
    } else {
        int src = t0 - s;
        v.x = (src >= 0 && src < TIME) ? row_in[src] : 0.0f;
        ++src;
        v.y = (src >= 0 && src < TIME) ? row_in[src] : 0.0f;
        ++src;
        v.z = (src >= 0 && src < TIME) ? row_in[src] : 0.0f;
        ++src;
        v.w = (src >= 0 && src < TIME) ? row_in[src] : 0.0f;
    }

    // t0 is a multiple of 4 and TIME % 4 == 0: in-bounds, 16B-aligned.
    __builtin_nontemporal_store(
        v, reinterpret_cast<f4a*>(out + (size_t)b * TIME + t0));
}

extern "C" void kernel_launch(void* const* d_in, const int* in_sizes, int n_in,
                              void* d_out, int out_size, void* d_ws, size_t ws_size,
                              hipStream_t stream) {
    const float* in = (const float*)d_in[0];
    const int* shifts = (const int*)d_in[1];
    float* out = (float*)d_out;

    dim3 block(BLOCK);
    dim3 grid((TIME + TILE - 1) / TILE, BATCH);
    random_shift_kernel<<<grid, block, 0, stream>>>(in, shifts, out);
}

// Round 5
// 42.278 us; speedup vs baseline: 1.0670x; 1.0670x over previous
//
#include <hip/hip_runtime.h>

// RandomShift: out[b,t] = in[b, t - s_b] if 0 <= t - s_b < T else 0.
// B=2048, T=16000, fp32. Memory-bound: ~262 MB total traffic.
//
// R1: uniform-tile fast path (shift is block-uniform) -> one unaligned
//     dwordx4 load per thread, no per-element checks. 43.7 us, ~6.0 TB/s.
// R3: nt on BOTH streams regressed to 45.1 us — nt loads drop the
//     tile/wave-boundary lines that overlapping misaligned reads re-use
//     from L2.
// R4: nt on the STORE only (write-once stream, skip L2 write-allocate);
//     loads back to normal cached path.

constexpr int BATCH = 2048;
constexpr int TIME = 16000;
constexpr int EPT = 4;            // elements per thread
constexpr int BLOCK = 256;
constexpr int TILE = BLOCK * EPT; // 1024

// Clang ext-vector float4 with only 4-byte alignment (misaligned wide load).
typedef float f4u __attribute__((ext_vector_type(4), aligned(4)));
// Clang ext-vector float4, naturally 16B-aligned (for the store).
typedef float f4a __attribute__((ext_vector_type(4)));

__global__ __launch_bounds__(BLOCK) void random_shift_kernel(
    const float* __restrict__ in,
    const int* __restrict__ shifts,
    float* __restrict__ out) {
    const int b = blockIdx.y;
    const int s = shifts[b];  // uniform per block -> scalar
    const int tile0 = blockIdx.x * TILE;
    const int t0 = tile0 + threadIdx.x * EPT;
    if (t0 >= TIME) return;

    const float* __restrict__ row_in = in + (size_t)b * TIME;
    const int tile_end = (tile0 + TILE < TIME) ? (tile0 + TILE) : TIME;

    f4a v;
    if (tile0 - s >= 0 && tile_end - s <= TIME) {
        // Whole tile maps to valid sources: single wide load, no checks.
        f4u lv = *reinterpret_cast<const f4u*>(row_in + (t0 - s));
        v.x = lv.x; v.y = lv.y; v.z = lv.z; v.w = lv.w;
    } else {
        int src = t0 - s;
        v.x = (src >= 0 && src < TIME) ? row_in[src] : 0.0f;
        ++src;
        v.y = (src >= 0 && src < TIME) ? row_in[src] : 0.0f;
        ++src;
        v.z = (src >= 0 && src < TIME) ? row_in[src] : 0.0f;
        ++src;
        v.w = (src >= 0 && src < TIME) ? row_in[src] : 0.0f;
    }

    // t0 is a multiple of 4 and TIME % 4 == 0: in-bounds, 16B-aligned.
    __builtin_nontemporal_store(
        v, reinterpret_cast<f4a*>(out + (size_t)b * TIME + t0));
}

extern "C" void kernel_launch(void* const* d_in, const int* in_sizes, int n_in,
                              void* d_out, int out_size, void* d_ws, size_t ws_size,
                              hipStream_t stream) {
    const float* in = (const float*)d_in[0];
    const int* shifts = (const int*)d_in[1];
    float* out = (float*)d_out;

    dim3 block(BLOCK);
    dim3 grid((TIME + TILE - 1) / TILE, BATCH);
    random_shift_kernel<<<grid, block, 0, stream>>>(in, shifts, out);
}